// Round 1
// baseline (1027.084 us; speedup 1.0000x reference)
//
#include <hip/hip_runtime.h>
#include <cstdint>

#define TK 2048     // tokens
#define DM 1024     // d_model
#define NE 8        // experts
#define NF 2048     // expert hidden
#define NV 32000    // vocab
#define CAP 640     // int(1.25 * 2 * 2048 / 8)

typedef short bf16x8 __attribute__((ext_vector_type(8)));
typedef float floatx4 __attribute__((ext_vector_type(4)));

__device__ __forceinline__ unsigned short f2bf(float x){
  unsigned u = __float_as_uint(x);
  u += 0x7FFFu + ((u >> 16) & 1u);
  return (unsigned short)(u >> 16);
}
__device__ __forceinline__ float bf2f(unsigned short h){
  return __uint_as_float(((unsigned)h) << 16);
}
__device__ __forceinline__ float gelu_tanh(float x){
  float x3 = x*x*x;
  return 0.5f*x*(1.0f + tanhf(0.7978845608028654f*(x + 0.044715f*x3)));
}

// ---------- fp32 -> bf16 convert (vectorized) ----------
__global__ void k_convert_bf16(const float* __restrict__ in, unsigned short* __restrict__ out, long n4){
  long i = (long)blockIdx.x*blockDim.x + threadIdx.x;
  if (i >= n4) return;
  float4 v = ((const float4*)in)[i];
  ushort4 o;
  o.x = f2bf(v.x); o.y = f2bf(v.y); o.z = f2bf(v.z); o.w = f2bf(v.w);
  ((ushort4*)out)[i] = o;
}

// ---------- batched transpose fp32 [B,R,C] -> bf16 hi/lo [B,C,R] ----------
__global__ void k_transpose_split(const float* __restrict__ in, unsigned short* __restrict__ hi,
                                  unsigned short* __restrict__ lo, int R, int C){
  __shared__ float tile[32][33];
  const int b = blockIdx.z;
  const float* src = in + (long)b*R*C;
  const int c0 = blockIdx.x*32, r0 = blockIdx.y*32;
  const int tx = threadIdx.x, ty = threadIdx.y;
#pragma unroll
  for (int j=0;j<4;j++){
    int rr = ty + j*8;
    tile[rr][tx] = src[(long)(r0+rr)*C + (c0+tx)];
  }
  __syncthreads();
  unsigned short* dh = hi + (long)b*R*C;
  unsigned short* dl = lo + (long)b*R*C;
#pragma unroll
  for (int j=0;j<4;j++){
    int cc = ty + j*8;
    float v = tile[tx][cc];
    long o = (long)(c0+cc)*R + (r0+tx);
    unsigned short h_ = f2bf(v);
    dh[o] = h_;
    dl[o] = f2bf(v - bf2f(h_));
  }
}

// ---------- embedding gather: h fp32 + hi/lo bf16 planes ----------
__global__ void k_gather(const int* __restrict__ ids, const float* __restrict__ embed,
                         float* __restrict__ h, unsigned short* __restrict__ h_hi,
                         unsigned short* __restrict__ h_lo){
  const int t = blockIdx.x, tid = threadIdx.x;
  const int id = ids[t];
  float4 v = ((const float4*)(embed + (long)id*DM))[tid];
  ((float4*)(h + (long)t*DM))[tid] = v;
  ushort4 hh, ll;
  hh.x = f2bf(v.x); ll.x = f2bf(v.x - bf2f(hh.x));
  hh.y = f2bf(v.y); ll.y = f2bf(v.y - bf2f(hh.y));
  hh.z = f2bf(v.z); ll.z = f2bf(v.z - bf2f(hh.z));
  hh.w = f2bf(v.w); ll.w = f2bf(v.w - bf2f(hh.w));
  ((ushort4*)(h_hi + (long)t*DM))[tid] = hh;
  ((ushort4*)(h_lo + (long)t*DM))[tid] = ll;
}

// ---------- router: one wave per token; fp32 logits, softmax, top-2 ----------
__global__ void k_router(const float* __restrict__ h, const float* __restrict__ rw,
                         int* __restrict__ topk_e, float* __restrict__ topk_p,
                         int* __restrict__ tok_slot){
  const int t = blockIdx.x, lane = threadIdx.x;
  float acc[NE];
#pragma unroll
  for (int e=0;e<NE;e++) acc[e]=0.f;
  for (int i=0;i<DM/64;i++){
    int d = i*64 + lane;
    float hv = h[(long)t*DM + d];
    float4 r0 = ((const float4*)(rw + (long)d*NE))[0];
    float4 r1 = ((const float4*)(rw + (long)d*NE))[1];
    acc[0]+=hv*r0.x; acc[1]+=hv*r0.y; acc[2]+=hv*r0.z; acc[3]+=hv*r0.w;
    acc[4]+=hv*r1.x; acc[5]+=hv*r1.y; acc[6]+=hv*r1.z; acc[7]+=hv*r1.w;
  }
#pragma unroll
  for (int e=0;e<NE;e++){
#pragma unroll
    for (int off=32; off>=1; off>>=1) acc[e] += __shfl_xor(acc[e], off, 64);
  }
  if (lane==0){
    int e1=-1; float v1=-1e30f;
    for (int e=0;e<NE;e++) if (acc[e] > v1){ v1=acc[e]; e1=e; }
    int e2=-1; float v2=-1e30f;
    for (int e=0;e<NE;e++) if (e!=e1 && acc[e] > v2){ v2=acc[e]; e2=e; }
    float s=0.f;
    for (int e=0;e<NE;e++) s += expf(acc[e]-v1);
    topk_e[2*t]   = e1;  topk_e[2*t+1] = e2;
    topk_p[2*t]   = 1.0f/s;
    topk_p[2*t+1] = expf(v2-v1)/s;
    tok_slot[2*t] = -1;  tok_slot[2*t+1] = -1;
  }
}

// ---------- capacity: 8 waves, one expert each; sequential ballot scan ----------
__global__ void k_capacity(const int* __restrict__ topk_e, int* __restrict__ slot_token,
                           int* __restrict__ tok_slot){
  const int e = threadIdx.x >> 6, lane = threadIdx.x & 63;
  int running = 0;
  for (int base=0; base<TK; base+=64){
    int t = base + lane;
    int ea = topk_e[2*t], eb = topk_e[2*t+1];
    bool m = (ea==e) || (eb==e);
    unsigned long long bm = __ballot(m);
    int pre = __popcll(bm & (~0ull >> (63-lane)));   // inclusive rank within chunk
    if (m){
      int rank = running + pre;                       // inclusive cumulative rank
      if (rank <= CAP){
        int slot = rank - 1;
        slot_token[e*CAP + slot] = t;
        int j = (ea==e) ? 0 : 1;
        tok_slot[2*t+j] = e*CAP + slot;
      }
    }
    running += __popcll(bm);
  }
  int total = running < CAP ? running : CAP;
  for (int s = total + lane; s < CAP; s += 64) slot_token[e*CAP+s] = -1;
}

// ---------- MFMA GEMM: C[M,N] = A[M,K] * B'[N,K]^T (NT), 128x128x32 tiles ----------
// SPLIT: 3-term hi/lo bf16 (near-fp32).  GATHER: A rows via slot_token list.
// EPI 0: fp32 store.  EPI 1: gelu -> bf16 (hi, + lo if SPLIT).
template<bool SPLIT, bool GATHER, int EPI>
__global__ __launch_bounds__(256) void k_gemm(
    const unsigned short* __restrict__ Ahi, const unsigned short* __restrict__ Alo,
    const unsigned short* __restrict__ Bhi, const unsigned short* __restrict__ Blo,
    const int* __restrict__ rows,
    float* __restrict__ Cf, unsigned short* __restrict__ Chi, unsigned short* __restrict__ Clo,
    int K, int lda, int ldb, int ldc,
    long sA, long sB, long sC)
{
  constexpr int LDSW = 40;   // 32 + 8 pad: 16B-aligned rows, benign 2-way banking
  __shared__ unsigned short As_hi[128*LDSW];
  __shared__ unsigned short Bs_hi[128*LDSW];
  __shared__ unsigned short As_lo[SPLIT ? 128*LDSW : 64];
  __shared__ unsigned short Bs_lo[SPLIT ? 128*LDSW : 64];

  const int bm = blockIdx.x, bn = blockIdx.y, bz = blockIdx.z;
  const int tid = threadIdx.x;
  const int wid = tid>>6, lane = tid&63;
  const int wm = wid>>1, wn = wid&1;
  const int quad = lane>>4, l16 = lane&15;
  const int r = tid>>1, ccol = (tid&1)*16;

  const unsigned short* Abh = Ahi + (long)bz*sA;
  const unsigned short* Abl = SPLIT ? (Alo + (long)bz*sA) : Ahi;
  const unsigned short* Bbh = Bhi + (long)bz*sB;
  const unsigned short* Bbl = SPLIT ? (Blo + (long)bz*sB) : Bhi;

  long arow; bool avalid;
  if constexpr (GATHER){
    int t = rows[bz*CAP + bm*128 + r];
    avalid = (t >= 0); arow = avalid ? t : 0;
  } else { avalid = true; arow = (long)bm*128 + r; }
  const long aoff = arow*(long)lda + ccol;
  const long boff = ((long)bn*128 + r)*(long)ldb + ccol;

  uint4 ra0, ra1, rb0, rb1, ra0l, ra1l, rb0l, rb1l;
  const uint4 zz = make_uint4(0,0,0,0);

  auto stage_load = [&](int k0){
    if (avalid){
      ra0 = *(const uint4*)(Abh + aoff + k0);
      ra1 = *(const uint4*)(Abh + aoff + k0 + 8);
      if constexpr (SPLIT){
        ra0l = *(const uint4*)(Abl + aoff + k0);
        ra1l = *(const uint4*)(Abl + aoff + k0 + 8);
      }
    } else {
      ra0 = zz; ra1 = zz;
      if constexpr (SPLIT){ ra0l = zz; ra1l = zz; }
    }
    rb0 = *(const uint4*)(Bbh + boff + k0);
    rb1 = *(const uint4*)(Bbh + boff + k0 + 8);
    if constexpr (SPLIT){
      rb0l = *(const uint4*)(Bbl + boff + k0);
      rb1l = *(const uint4*)(Bbl + boff + k0 + 8);
    }
  };
  auto stage_store = [&](){
    *(uint4*)&As_hi[r*LDSW + ccol]     = ra0;
    *(uint4*)&As_hi[r*LDSW + ccol + 8] = ra1;
    *(uint4*)&Bs_hi[r*LDSW + ccol]     = rb0;
    *(uint4*)&Bs_hi[r*LDSW + ccol + 8] = rb1;
    if constexpr (SPLIT){
      *(uint4*)&As_lo[r*LDSW + ccol]     = ra0l;
      *(uint4*)&As_lo[r*LDSW + ccol + 8] = ra1l;
      *(uint4*)&Bs_lo[r*LDSW + ccol]     = rb0l;
      *(uint4*)&Bs_lo[r*LDSW + ccol + 8] = rb1l;
    }
  };

  floatx4 acc[4][4] = {};
  const int KT = K >> 5;
  stage_load(0);
  for (int kt=0; kt<KT; ++kt){
    __syncthreads();
    stage_store();
    __syncthreads();
    if (kt+1 < KT) stage_load((kt+1) << 5);

    bf16x8 ah[4], bh[4];
#pragma unroll
    for (int i=0;i<4;i++){
      ah[i] = *(const bf16x8*)&As_hi[(wm*64 + i*16 + l16)*LDSW + quad*8];
      bh[i] = *(const bf16x8*)&Bs_hi[(wn*64 + i*16 + l16)*LDSW + quad*8];
    }
#pragma unroll
    for (int mt=0;mt<4;mt++)
#pragma unroll
      for (int nt=0;nt<4;nt++)
        acc[mt][nt] = __builtin_amdgcn_mfma_f32_16x16x32_bf16(ah[mt], bh[nt], acc[mt][nt], 0,0,0);
    if constexpr (SPLIT){
      bf16x8 al[4], bl[4];
#pragma unroll
      for (int i=0;i<4;i++){
        al[i] = *(const bf16x8*)&As_lo[(wm*64 + i*16 + l16)*LDSW + quad*8];
        bl[i] = *(const bf16x8*)&Bs_lo[(wn*64 + i*16 + l16)*LDSW + quad*8];
      }
#pragma unroll
      for (int mt=0;mt<4;mt++)
#pragma unroll
        for (int nt=0;nt<4;nt++){
          acc[mt][nt] = __builtin_amdgcn_mfma_f32_16x16x32_bf16(ah[mt], bl[nt], acc[mt][nt], 0,0,0);
          acc[mt][nt] = __builtin_amdgcn_mfma_f32_16x16x32_bf16(al[mt], bh[nt], acc[mt][nt], 0,0,0);
        }
    }
  }

  // epilogue: C/D layout col=lane&15, row=quad*4+reg (m89-verified)
  if constexpr (EPI == 0){
    float* Cb = Cf + (long)bz*sC;
#pragma unroll
    for (int mt=0;mt<4;mt++)
#pragma unroll
      for (int nt=0;nt<4;nt++)
#pragma unroll
        for (int i=0;i<4;i++){
          int gr = bm*128 + wm*64 + mt*16 + quad*4 + i;
          int gc = bn*128 + wn*64 + nt*16 + l16;
          Cb[(long)gr*ldc + gc] = acc[mt][nt][i];
        }
  } else {
    unsigned short* Ch = Chi + (long)bz*sC;
    unsigned short* Cl = nullptr;
    if constexpr (SPLIT) Cl = Clo + (long)bz*sC;
#pragma unroll
    for (int mt=0;mt<4;mt++)
#pragma unroll
      for (int nt=0;nt<4;nt++)
#pragma unroll
        for (int i=0;i<4;i++){
          int gr = bm*128 + wm*64 + mt*16 + quad*4 + i;
          int gc = bn*128 + wn*64 + nt*16 + l16;
          float g = gelu_tanh(acc[mt][nt][i]);
          unsigned short hh = f2bf(g);
          long o = (long)gr*ldc + gc;
          Ch[o] = hh;
          if constexpr (SPLIT) Cl[o] = f2bf(g - bf2f(hh));
        }
  }
}

// ---------- combine: h = (1-rho)*h + sum_j w_j * out_e[slot_j] ----------
__global__ void k_combine(float* __restrict__ h, unsigned short* __restrict__ h_hi,
                          const float* __restrict__ out_e,
                          const int* __restrict__ tok_slot, const float* __restrict__ topk_p){
  const int t = blockIdx.x, tid = threadIdx.x;
  const int s0 = tok_slot[2*t], s1 = tok_slot[2*t+1];
  const float w0 = (s0>=0) ? topk_p[2*t]   : 0.f;
  const float w1 = (s1>=0) ? topk_p[2*t+1] : 0.f;
  const float sc = 1.f - w0 - w1;
#pragma unroll
  for (int i=0;i<4;i++){
    int d = i*256 + tid;
    float v = sc * h[(long)t*DM + d];
    if (s0>=0) v += w0 * out_e[(long)s0*DM + d];
    if (s1>=0) v += w1 * out_e[(long)s1*DM + d];
    h[(long)t*DM + d] = v;
    h_hi[(long)t*DM + d] = f2bf(v);
  }
}

// ---------- rmsnorm -> bf16 ----------
__global__ void k_rmsnorm(const float* __restrict__ h, const float* __restrict__ lnw,
                          unsigned short* __restrict__ h_hi){
  const int t = blockIdx.x, tid = threadIdx.x;
  const int wid = tid>>6, lane = tid&63;
  float vals[4];
  float ss = 0.f;
#pragma unroll
  for (int i=0;i<4;i++){ vals[i] = h[(long)t*DM + i*256 + tid]; ss += vals[i]*vals[i]; }
#pragma unroll
  for (int off=32; off>=1; off>>=1) ss += __shfl_xor(ss, off, 64);
  __shared__ float red[4];
  __shared__ float scale_s;
  if (lane==0) red[wid] = ss;
  __syncthreads();
  if (tid==0) scale_s = 1.0f / sqrtf((red[0]+red[1]+red[2]+red[3])/(float)DM + 1e-6f);
  __syncthreads();
  float scale = scale_s;
#pragma unroll
  for (int i=0;i<4;i++){
    int d = i*256 + tid;
    h_hi[(long)t*DM + d] = f2bf(vals[i]*scale*lnw[d]);
  }
}

extern "C" void kernel_launch(void* const* d_in, const int* in_sizes, int n_in,
                              void* d_out, int out_size, void* d_ws, size_t ws_size,
                              hipStream_t stream){
  const int*   ids   = (const int*)d_in[0];
  const float* embed = (const float*)d_in[1];
  const float* rw    = (const float*)d_in[2];
  const float* w1    = (const float*)d_in[3];
  const float* w2    = (const float*)d_in[4];
  const float* lnw   = (const float*)d_in[5];

  // ws carve (~82.4 MB)
  char* ws = (char*)d_ws;
  auto alloc = [&](size_t b)->char*{ char* p = ws; ws += (b + 255) & ~(size_t)255; return p; };
  unsigned short* embed_bf = (unsigned short*)alloc((size_t)NV*DM*2);
  float*          h        = (float*)alloc((size_t)TK*DM*4);
  unsigned short* h_hi     = (unsigned short*)alloc((size_t)TK*DM*2);
  unsigned short* h_lo     = (unsigned short*)alloc((size_t)TK*DM*2);
  int*   topk_e   = (int*)alloc(TK*2*4);
  float* topk_p   = (float*)alloc(TK*2*4);
  int*   tok_slot = (int*)alloc(TK*2*4);
  int*   slot_tok = (int*)alloc(NE*CAP*4);

  // d_out doubles as scratch (~197 MB < 262 MB); final GEMM overwrites all of it
  char* od = (char*)d_out;
  auto alloc2 = [&](size_t b)->char*{ char* p = od; od += (b + 255) & ~(size_t)255; return p; };
  unsigned short* w1t_hi = (unsigned short*)alloc2((size_t)NE*DM*NF*2);
  unsigned short* w1t_lo = (unsigned short*)alloc2((size_t)NE*DM*NF*2);
  unsigned short* w2t_hi = (unsigned short*)alloc2((size_t)NE*DM*NF*2);
  unsigned short* w2t_lo = (unsigned short*)alloc2((size_t)NE*DM*NF*2);
  unsigned short* act_hi = (unsigned short*)alloc2((size_t)NE*CAP*NF*2);
  unsigned short* act_lo = (unsigned short*)alloc2((size_t)NE*CAP*NF*2);
  float*          out_e  = (float*)alloc2((size_t)NE*CAP*DM*4);

  dim3 tb32(32,8,1);
  // weights -> NT-layout bf16 hi/lo planes
  k_transpose_split<<<dim3(NF/32, DM/32, NE), tb32, 0, stream>>>(w1, w1t_hi, w1t_lo, DM, NF);
  k_transpose_split<<<dim3(DM/32, NF/32, NE), tb32, 0, stream>>>(w2, w2t_hi, w2t_lo, NF, DM);
  k_convert_bf16<<<(int)(((long)NV*DM/4 + 255)/256), 256, 0, stream>>>(embed, embed_bf, (long)NV*DM/4);
  k_gather<<<TK, 256, 0, stream>>>(ids, embed, h, h_hi, h_lo);

  for (int hop=0; hop<2; ++hop){
    k_router<<<TK, 64, 0, stream>>>(h, rw + (long)hop*DM*NE, topk_e, topk_p, tok_slot);
    k_capacity<<<1, 512, 0, stream>>>(topk_e, slot_tok, tok_slot);
    if (hop == 0){
      // split-precision hop 0: protects hop-1 routing decisions
      k_gemm<true,true,1><<<dim3(CAP/128, NF/128, NE), 256, 0, stream>>>(
        h_hi, h_lo, w1t_hi, w1t_lo, slot_tok, nullptr, act_hi, act_lo,
        DM, DM, DM, NF, 0L, (long)NF*DM, (long)CAP*NF);
      k_gemm<true,false,0><<<dim3(CAP/128, DM/128, NE), 256, 0, stream>>>(
        act_hi, act_lo, w2t_hi, w2t_lo, nullptr, out_e, nullptr, nullptr,
        NF, NF, NF, DM, (long)CAP*NF, (long)DM*NF, (long)CAP*DM);
    } else {
      k_gemm<false,true,1><<<dim3(CAP/128, NF/128, NE), 256, 0, stream>>>(
        h_hi, nullptr, w1t_hi, nullptr, slot_tok, nullptr, act_hi, nullptr,
        DM, DM, DM, NF, 0L, (long)NF*DM, (long)CAP*NF);
      k_gemm<false,false,0><<<dim3(CAP/128, DM/128, NE), 256, 0, stream>>>(
        act_hi, nullptr, w2t_hi, nullptr, nullptr, out_e, nullptr, nullptr,
        NF, NF, NF, DM, (long)CAP*NF, (long)DM*NF, (long)CAP*DM);
    }
    k_combine<<<TK, 256, 0, stream>>>(h, h_hi, out_e, tok_slot, topk_p);
  }

  k_rmsnorm<<<TK, 256, 0, stream>>>(h, lnw, h_hi);
  // final tied projection: [2048,1024] x [32000,1024]^T -> d_out fp32
  k_gemm<false,false,0><<<dim3(TK/128, NV/128, 1), 256, 0, stream>>>(
    h_hi, nullptr, embed_bf, nullptr, nullptr, (float*)d_out, nullptr, nullptr,
    DM, DM, DM, NV, 0L, 0L, 0L);
}